// Round 2
// baseline (918.993 us; speedup 1.0000x reference)
//
#include <hip/hip_runtime.h>
#include <hip/hip_bf16.h>
#include <math.h>

// ---------------------------------------------------------------------------
// FuncGNN R14: gather rewritten for memory-level parallelism. R13's gather had
// VGPR_Count=12 -> compiler register-serialized the 8 "independent" ushort row
// loads, exposing full L2/HBM latency every ~2 edges. New form: uint4 loads
// (16B = 8 bf16 cols/lane, 8 lanes/row) -> 8 edge-rows per load instruction,
// 16 edges in flight per wave with payload prefetched a batch ahead.
// Everything outside gather64 is identical to R13 (867.8 us, passed).
// ---------------------------------------------------------------------------

#define NBSHIFT 9           // 512 nodes per bucket
#define NBSIZE  512

__device__ __forceinline__ float gelu_f(float x) {
    return 0.5f * x * (1.0f + erff(x * 0.70710678118654752440f));
}
__device__ __forceinline__ unsigned short f2bf(float x) {
    __hip_bfloat16 h = __float2bfloat16(x);      // RNE
    return *reinterpret_cast<unsigned short*>(&h);
}
__device__ __forceinline__ unsigned pack2bf(float a, float b) {
    return (unsigned)f2bf(a) | ((unsigned)f2bf(b) << 16);
}
__device__ __forceinline__ float bf2f(unsigned short u) {
    return __uint_as_float((unsigned)u << 16);
}

// ------------- gemm64: Cb[n,64](bf16) = A @ Wa + ba  (p=0 only) --------------
__global__ __launch_bounds__(256) void gemm64(
    const float* __restrict__ A,
    const float* __restrict__ Wa, const float* __restrict__ ba,
    unsigned short* __restrict__ Cb, int n)
{
    __shared__ __align__(16) float At[64][68];
    __shared__ __align__(16) float Ws[64][68];
    const int tid = threadIdx.x;
    const int tx = tid & 15, ty = tid >> 4;
    const int rowBase = blockIdx.x * 64;

    #pragma unroll
    for (int i = 0; i < 4; ++i) {
        int v  = tid + i * 256;
        int r  = v >> 4;
        int k4 = (v & 15) * 4;
        float4 a = make_float4(0.f, 0.f, 0.f, 0.f);
        int grow = rowBase + r;
        if (grow < n) a = *(const float4*)(A + (size_t)grow * 64 + k4);
        At[k4 + 0][r] = a.x; At[k4 + 1][r] = a.y;
        At[k4 + 2][r] = a.z; At[k4 + 3][r] = a.w;
        *(float4*)&Ws[r][k4] = *(const float4*)(Wa + r * 64 + k4);
    }
    __syncthreads();

    const int r0 = ty * 4, c0 = tx * 4;
    float acc[4][4];
    #pragma unroll
    for (int j = 0; j < 4; ++j) {
        float bv = ba[c0 + j];
        #pragma unroll
        for (int i = 0; i < 4; ++i) acc[i][j] = bv;
    }
    #pragma unroll 16
    for (int k = 0; k < 64; ++k) {
        float4 av = *(const float4*)&At[k][r0];
        float4 wv = *(const float4*)&Ws[k][c0];
        float a4[4] = {av.x, av.y, av.z, av.w};
        float w4[4] = {wv.x, wv.y, wv.z, wv.w};
        #pragma unroll
        for (int i = 0; i < 4; ++i)
            #pragma unroll
            for (int j = 0; j < 4; ++j)
                acc[i][j] = fmaf(a4[i], w4[j], acc[i][j]);
    }
    #pragma unroll
    for (int i = 0; i < 4; ++i) {
        int grow = rowBase + r0 + i;
        if (grow < n) {
            uint2 u;
            u.x = pack2bf(acc[i][0], acc[i][1]);
            u.y = pack2bf(acc[i][2], acc[i][3]);
            *(uint2*)(Cb + (size_t)grow * 64 + c0) = u;
        }
    }
}

// -- act_fuse: graph-norm scale/offset in-block; x=gelu(h*a+b) (bf16 only);
//    xfinal (+)= x @ Wf (+bf if FIRST) ---------------------------------------
template<bool FIRST>
__global__ __launch_bounds__(256) void act_fuse(
    const float* __restrict__ h,
    const float* __restrict__ colsum, const float* __restrict__ colsumsq,
    const float* __restrict__ nw, const float* __restrict__ nb,
    const float* __restrict__ rsw, const float* __restrict__ rsb,
    const float* __restrict__ rbw, const float* __restrict__ rbb,
    const float* __restrict__ rate_p, float inv_n,
    const float* __restrict__ Wf, const float* __restrict__ bf,
    unsigned short* __restrict__ xb, float* __restrict__ xfinal, int n)
{
    __shared__ __align__(16) float At[64][68];
    __shared__ __align__(16) float Ws[64][68];
    __shared__ float ab_s[128];
    const int tid = threadIdx.x;
    const int tx = tid & 15, ty = tid >> 4;
    const int rowBase = blockIdx.x * 64;

    if (tid < 64) {
        float mean = colsum[tid] * inv_n;
        float var  = colsumsq[tid] * inv_n - mean * mean;
        float rstd = rsqrtf(var + 1e-5f);
        float rate = rate_p[0];
        float gamma = nw[tid] + (rsw[tid] * rate + rsb[tid]);
        float beta  = nb[tid] + (rbw[tid] * rate + rbb[tid]);
        float a = rstd * gamma;
        ab_s[tid] = a;
        ab_s[64 + tid] = beta - mean * a;
    }
    __syncthreads();

    #pragma unroll
    for (int i = 0; i < 4; ++i) {
        int v  = tid + i * 256;
        int r  = v >> 4;
        int k4 = (v & 15) * 4;
        int grow = rowBase + r;
        float4 a = make_float4(0.f, 0.f, 0.f, 0.f);
        if (grow < n) {
            float4 hv = *(const float4*)(h + (size_t)grow * 64 + k4);
            a.x = gelu_f(fmaf(hv.x, ab_s[k4 + 0], ab_s[64 + k4 + 0]));
            a.y = gelu_f(fmaf(hv.y, ab_s[k4 + 1], ab_s[64 + k4 + 1]));
            a.z = gelu_f(fmaf(hv.z, ab_s[k4 + 2], ab_s[64 + k4 + 2]));
            a.w = gelu_f(fmaf(hv.w, ab_s[k4 + 3], ab_s[64 + k4 + 3]));
            uint2 u;
            u.x = pack2bf(a.x, a.y);
            u.y = pack2bf(a.z, a.w);
            *(uint2*)(xb + (size_t)grow * 64 + k4) = u;
        }
        At[k4 + 0][r] = a.x; At[k4 + 1][r] = a.y;
        At[k4 + 2][r] = a.z; At[k4 + 3][r] = a.w;
        *(float4*)&Ws[r][k4] = *(const float4*)(Wf + r * 64 + k4);
    }
    __syncthreads();

    const int r0 = ty * 4, c0 = tx * 4;
    float acc[4][4];
    if (FIRST) {
        #pragma unroll
        for (int j = 0; j < 4; ++j) {
            float bv = bf[c0 + j];
            #pragma unroll
            for (int i = 0; i < 4; ++i) acc[i][j] = bv;
        }
    } else {
        #pragma unroll
        for (int i = 0; i < 4; ++i)
            #pragma unroll
            for (int j = 0; j < 4; ++j) acc[i][j] = 0.f;
    }
    #pragma unroll 16
    for (int k = 0; k < 64; ++k) {
        float4 av = *(const float4*)&At[k][r0];
        float4 wv = *(const float4*)&Ws[k][c0];
        float a4[4] = {av.x, av.y, av.z, av.w};
        float w4[4] = {wv.x, wv.y, wv.z, wv.w};
        #pragma unroll
        for (int i = 0; i < 4; ++i)
            #pragma unroll
            for (int j = 0; j < 4; ++j)
                acc[i][j] = fmaf(a4[i], w4[j], acc[i][j]);
    }
    #pragma unroll
    for (int i = 0; i < 4; ++i) {
        int grow = rowBase + r0 + i;
        if (grow < n) {
            float4 r = make_float4(acc[i][0], acc[i][1], acc[i][2], acc[i][3]);
            float* cp = xfinal + (size_t)grow * 64 + c0;
            if (!FIRST) {
                float4 c = *(const float4*)cp;
                r.x += c.x; r.y += c.y; r.z += c.z; r.w += c.w;
            }
            *(float4*)cp = r;
        }
    }
}

// -- gin_fuse: t=gelu(z@W1+b1); o=t@W2+b2 -> xout; xfinal += o@Wf;
//    if NEXT: bfout = bf16(o @ Wn + bn)   (next pair's SAGE xt) --------------
template<bool NEXT>
__global__ __launch_bounds__(256) void gin_fuse(
    const float* __restrict__ z,
    const float* __restrict__ W1, const float* __restrict__ b1,
    const float* __restrict__ W2, const float* __restrict__ b2,
    const float* __restrict__ Wf,
    const float* __restrict__ Wn, const float* __restrict__ bn,
    float* __restrict__ xout, float* __restrict__ xfinal,
    unsigned short* __restrict__ bfout, int n)
{
    __shared__ __align__(16) float At[64][68];
    __shared__ __align__(16) float Ws[64][68];
    const int tid = threadIdx.x;
    const int tx = tid & 15, ty = tid >> 4;
    const int rowBase = blockIdx.x * 64;
    const int r0 = ty * 4, c0 = tx * 4;

    #pragma unroll
    for (int i = 0; i < 4; ++i) {
        int v  = tid + i * 256;
        int r  = v >> 4;
        int k4 = (v & 15) * 4;
        float4 a = make_float4(0.f, 0.f, 0.f, 0.f);
        int grow = rowBase + r;
        if (grow < n) a = *(const float4*)(z + (size_t)grow * 64 + k4);
        At[k4 + 0][r] = a.x; At[k4 + 1][r] = a.y;
        At[k4 + 2][r] = a.z; At[k4 + 3][r] = a.w;
        *(float4*)&Ws[r][k4] = *(const float4*)(W1 + r * 64 + k4);
    }
    __syncthreads();

    float acc[4][4];
    #pragma unroll
    for (int j = 0; j < 4; ++j) {
        float bv = b1[c0 + j];
        #pragma unroll
        for (int i = 0; i < 4; ++i) acc[i][j] = bv;
    }
    #pragma unroll 16
    for (int k = 0; k < 64; ++k) {
        float4 av = *(const float4*)&At[k][r0];
        float4 wv = *(const float4*)&Ws[k][c0];
        float a4[4] = {av.x, av.y, av.z, av.w};
        float w4[4] = {wv.x, wv.y, wv.z, wv.w};
        #pragma unroll
        for (int i = 0; i < 4; ++i)
            #pragma unroll
            for (int j = 0; j < 4; ++j)
                acc[i][j] = fmaf(a4[i], w4[j], acc[i][j]);
    }

    // ---- GEMM2: gelu(acc) @ W2 + b2
    __syncthreads();
    #pragma unroll
    for (int i = 0; i < 4; ++i)
        #pragma unroll
        for (int j = 0; j < 4; ++j)
            At[c0 + j][r0 + i] = gelu_f(acc[i][j]);
    #pragma unroll
    for (int i = 0; i < 4; ++i) {
        int v = tid + i * 256;
        int k = v >> 4, c4 = (v & 15) * 4;
        *(float4*)&Ws[k][c4] = *(const float4*)(W2 + k * 64 + c4);
    }
    __syncthreads();
    float acc2[4][4];
    #pragma unroll
    for (int j = 0; j < 4; ++j) {
        float bv = b2[c0 + j];
        #pragma unroll
        for (int i = 0; i < 4; ++i) acc2[i][j] = bv;
    }
    #pragma unroll 16
    for (int k = 0; k < 64; ++k) {
        float4 av = *(const float4*)&At[k][r0];
        float4 wv = *(const float4*)&Ws[k][c0];
        float a4[4] = {av.x, av.y, av.z, av.w};
        float w4[4] = {wv.x, wv.y, wv.z, wv.w};
        #pragma unroll
        for (int i = 0; i < 4; ++i)
            #pragma unroll
            for (int j = 0; j < 4; ++j)
                acc2[i][j] = fmaf(a4[i], w4[j], acc2[i][j]);
    }
    #pragma unroll
    for (int i = 0; i < 4; ++i) {
        int grow = rowBase + r0 + i;
        if (grow < n)
            *(float4*)(xout + (size_t)grow * 64 + c0) =
                make_float4(acc2[i][0], acc2[i][1], acc2[i][2], acc2[i][3]);
    }

    // ---- GEMM3: xfinal += acc2 @ Wf   (At <- acc2^T, reused by GEMM4)
    __syncthreads();
    #pragma unroll
    for (int i = 0; i < 4; ++i)
        #pragma unroll
        for (int j = 0; j < 4; ++j)
            At[c0 + j][r0 + i] = acc2[i][j];
    #pragma unroll
    for (int i = 0; i < 4; ++i) {
        int v = tid + i * 256;
        int k = v >> 4, c4 = (v & 15) * 4;
        *(float4*)&Ws[k][c4] = *(const float4*)(Wf + k * 64 + c4);
    }
    __syncthreads();
    float acc3[4][4];
    #pragma unroll
    for (int i = 0; i < 4; ++i)
        #pragma unroll
        for (int j = 0; j < 4; ++j) acc3[i][j] = 0.f;
    #pragma unroll 16
    for (int k = 0; k < 64; ++k) {
        float4 av = *(const float4*)&At[k][r0];
        float4 wv = *(const float4*)&Ws[k][c0];
        float a4[4] = {av.x, av.y, av.z, av.w};
        float w4[4] = {wv.x, wv.y, wv.z, wv.w};
        #pragma unroll
        for (int i = 0; i < 4; ++i)
            #pragma unroll
            for (int j = 0; j < 4; ++j)
                acc3[i][j] = fmaf(a4[i], w4[j], acc3[i][j]);
    }
    #pragma unroll
    for (int i = 0; i < 4; ++i) {
        int grow = rowBase + r0 + i;
        if (grow < n) {
            float* cp = xfinal + (size_t)grow * 64 + c0;
            float4 c = *(const float4*)cp;
            c.x += acc3[i][0]; c.y += acc3[i][1];
            c.z += acc3[i][2]; c.w += acc3[i][3];
            *(float4*)cp = c;
        }
    }

    if (NEXT) {
        // ---- GEMM4: bfout = bf16(acc2 @ Wn + bn); At still holds acc2^T
        __syncthreads();
        #pragma unroll
        for (int i = 0; i < 4; ++i) {
            int v = tid + i * 256;
            int k = v >> 4, c4 = (v & 15) * 4;
            *(float4*)&Ws[k][c4] = *(const float4*)(Wn + k * 64 + c4);
        }
        __syncthreads();
        float acc4[4][4];
        #pragma unroll
        for (int j = 0; j < 4; ++j) {
            float bv = bn[c0 + j];
            #pragma unroll
            for (int i = 0; i < 4; ++i) acc4[i][j] = bv;
        }
        #pragma unroll 16
        for (int k = 0; k < 64; ++k) {
            float4 av = *(const float4*)&At[k][r0];
            float4 wv = *(const float4*)&Ws[k][c0];
            float a4[4] = {av.x, av.y, av.z, av.w};
            float w4[4] = {wv.x, wv.y, wv.z, wv.w};
            #pragma unroll
            for (int i = 0; i < 4; ++i)
                #pragma unroll
                for (int j = 0; j < 4; ++j)
                    acc4[i][j] = fmaf(a4[i], w4[j], acc4[i][j]);
        }
        #pragma unroll
        for (int i = 0; i < 4; ++i) {
            int grow = rowBase + r0 + i;
            if (grow < n) {
                uint2 u;
                u.x = pack2bf(acc4[i][0], acc4[i][1]);
                u.y = pack2bf(acc4[i][2], acc4[i][3]);
                *(uint2*)(bfout + (size_t)grow * 64 + c0) = u;
            }
        }
    }
}

// ---------------- bucket-sorted CSR build ------------------------------------
__global__ void init_buckets(int* __restrict__ bucket_cursor, int Bn, int cap) {
    int t = threadIdx.x;
    if (t < Bn) bucket_cursor[t] = t * cap;
}

__global__ __launch_bounds__(256) void bucketA(
    const int* __restrict__ eidx, int* __restrict__ bucket_cursor,
    uint2* __restrict__ inter, int E)
{
    __shared__ int cnt[256], lo[256], cur[256], garr[256];
    __shared__ int tot_s;
    __shared__ uint2 stage[4096];
    const int tid = threadIdx.x;
    cnt[tid] = 0;
    __syncthreads();

    const int base = blockIdx.x * 4096;
    int pay[16], dfull[16];
    #pragma unroll
    for (int i = 0; i < 16; ++i) {
        int e = base + i * 256 + tid;
        dfull[i] = -1;
        if (e < E) {
            int s  = __builtin_nontemporal_load(eidx + e * 3 + 0);
            int d  = __builtin_nontemporal_load(eidx + e * 3 + 1);
            int sg = __builtin_nontemporal_load(eidx + e * 3 + 2);
            if (sg < 0) s |= 0x80000000;
            pay[i] = s;
            dfull[i] = d;
            atomicAdd(&cnt[d >> NBSHIFT], 1);
        }
    }
    __syncthreads();

    lo[tid] = cnt[tid];
    __syncthreads();
    for (int off = 1; off < 256; off <<= 1) {
        int t = (tid >= off) ? lo[tid - off] : 0;
        __syncthreads();
        lo[tid] += t;
        __syncthreads();
    }
    if (tid == 255) tot_s = lo[255];
    int excl = lo[tid] - cnt[tid];
    __syncthreads();
    lo[tid] = excl;
    cur[tid] = 0;
    if (cnt[tid] > 0) garr[tid] = atomicAdd(bucket_cursor + tid, cnt[tid]);
    __syncthreads();

    #pragma unroll
    for (int i = 0; i < 16; ++i) {
        if (dfull[i] >= 0) {
            int k = dfull[i] >> NBSHIFT;
            int r = atomicAdd(&cur[k], 1);
            stage[lo[k] + r] = make_uint2((unsigned)pay[i], (unsigned)dfull[i]);
        }
    }
    __syncthreads();

    const int tot = tot_s;
    for (int i = tid; i < tot; i += 256) {
        uint2 en = stage[i];
        int k = (int)(en.y >> NBSHIFT);
        inter[garr[k] + (i - lo[k])] = en;
    }
}

__global__ __launch_bounds__(256) void bucketB1(
    const uint2* __restrict__ inter, const int* __restrict__ bucket_cursor,
    int* __restrict__ deg_i, int cap, int n)
{
    __shared__ int cnt[NBSIZE];
    const int b = blockIdx.x, tid = threadIdx.x;
    cnt[tid] = 0; cnt[tid + 256] = 0;
    __syncthreads();
    const int base = b * cap;
    const int len = bucket_cursor[b] - base;
    for (int i = tid; i < len; i += 256)
        atomicAdd(&cnt[inter[base + i].y & (NBSIZE - 1)], 1);
    __syncthreads();
    const int nb0 = b << NBSHIFT;
    if (nb0 + tid < n)       deg_i[nb0 + tid]       = cnt[tid];
    if (nb0 + 256 + tid < n) deg_i[nb0 + 256 + tid] = cnt[256 + tid];
}

__global__ __launch_bounds__(256) void bucketB2(
    const uint2* __restrict__ inter, const int* __restrict__ bucket_cursor,
    const int* __restrict__ row_ptr, int* __restrict__ payload, int cap, int n)
{
    __shared__ int cur[NBSIZE];
    const int b = blockIdx.x, tid = threadIdx.x;
    const int nb0 = b << NBSHIFT;
    cur[tid]       = (nb0 + tid < n)       ? row_ptr[nb0 + tid]       : 0;
    cur[tid + 256] = (nb0 + 256 + tid < n) ? row_ptr[nb0 + 256 + tid] : 0;
    __syncthreads();
    const int base = b * cap;
    const int len = bucket_cursor[b] - base;
    for (int i = tid; i < len; i += 256) {
        uint2 en = inter[base + i];
        int pos = atomicAdd(&cur[en.y & (NBSIZE - 1)], 1);
        payload[pos] = (int)en.x;
    }
}

// ---------------- scans ------------------------------------------------------
__global__ __launch_bounds__(256) void scan1(
    const int* __restrict__ deg_i, int* __restrict__ blocksum, int n, int chunk)
{
    int b = blockIdx.x;
    int lo = b * chunk, hi = min(lo + chunk, n);
    int s = 0;
    for (int i = lo + (int)threadIdx.x; i < hi; i += 256) s += deg_i[i];
    #pragma unroll
    for (int off = 32; off; off >>= 1) s += __shfl_xor(s, off, 64);
    __shared__ int ws[4];
    if ((threadIdx.x & 63) == 0) ws[threadIdx.x >> 6] = s;
    __syncthreads();
    if (threadIdx.x == 0) blocksum[b] = ws[0] + ws[1] + ws[2] + ws[3];
}

__global__ __launch_bounds__(256) void scan2(
    const int* __restrict__ blocksum, int* __restrict__ blockoff,
    int* __restrict__ row_ptr_n)
{
    int tid = threadIdx.x, lane = tid & 63, wid = tid >> 6;
    int orig = blocksum[tid];
    int v = orig;
    #pragma unroll
    for (int off = 1; off < 64; off <<= 1) {
        int t = __shfl_up(v, off, 64);
        if (lane >= off) v += t;
    }
    __shared__ int wt[4];
    if (lane == 63) wt[wid] = v;
    __syncthreads();
    int woff = 0;
    for (int w = 0; w < wid; ++w) woff += wt[w];
    blockoff[tid] = woff + v - orig;
    if (tid == 255) *row_ptr_n = woff + v;
}

__global__ __launch_bounds__(256) void scan3(
    const int* __restrict__ deg_i, const int* __restrict__ blockoff,
    int* __restrict__ row_ptr, float* __restrict__ rdeg, int n, int chunk)
{
    int b = blockIdx.x;
    int lo = b * chunk, hi = min(lo + chunk, n);
    int carry = blockoff[b];
    int tid = threadIdx.x, lane = tid & 63, wid = tid >> 6;
    __shared__ int wt[4];
    for (int base = lo; base < hi; base += 256) {
        int i = base + tid;
        int orig = (i < hi) ? deg_i[i] : 0;
        int v = orig;
        #pragma unroll
        for (int off = 1; off < 64; off <<= 1) {
            int t = __shfl_up(v, off, 64);
            if (lane >= off) v += t;
        }
        if (lane == 63) wt[wid] = v;
        __syncthreads();
        int woff = 0;
        for (int w = 0; w < wid; ++w) woff += wt[w];
        int tot = wt[0] + wt[1] + wt[2] + wt[3];
        int excl = carry + woff + (v - orig);
        if (i < hi) {
            row_ptr[i] = excl;
            rdeg[i]    = 1.0f / ((float)orig + 1.0f);
        }
        carry += tot;
        __syncthreads();
    }
}

// ------- gather R14: wave per node; uint4 row loads (8 rows/instr),
//         16 edges in flight, payload prefetched a batch ahead ---------------
__device__ __forceinline__ void accum8(float* a, uint4 u, float s) {
    a[0] = fmaf(__uint_as_float(u.x << 16),          s, a[0]);
    a[1] = fmaf(__uint_as_float(u.x & 0xffff0000u),  s, a[1]);
    a[2] = fmaf(__uint_as_float(u.y << 16),          s, a[2]);
    a[3] = fmaf(__uint_as_float(u.y & 0xffff0000u),  s, a[3]);
    a[4] = fmaf(__uint_as_float(u.z << 16),          s, a[4]);
    a[5] = fmaf(__uint_as_float(u.z & 0xffff0000u),  s, a[5]);
    a[6] = fmaf(__uint_as_float(u.w << 16),          s, a[6]);
    a[7] = fmaf(__uint_as_float(u.w & 0xffff0000u),  s, a[7]);
}

template<bool SAGE>
__global__ __launch_bounds__(256) void gather64(
    const int* __restrict__ row_ptr, const int* __restrict__ payload,
    const unsigned short* __restrict__ valb, const float* __restrict__ xprev,
    const float* __restrict__ rdeg, float* __restrict__ out,
    float* __restrict__ colsum, float* __restrict__ colsumsq, int n)
{
    const int tid  = threadIdx.x;
    const int lane = tid & 63;
    const int sub  = lane >> 3;          // edge slot 0..7
    const int c0   = (lane & 7) * 8;     // 8 bf16 cols per lane
    const int wid  = tid >> 6;
    int gw = (blockIdx.x * 256 + tid) >> 6;
    int nw = (gridDim.x * 256) >> 6;

    float st[8], st2[8];
    if (SAGE) {
        #pragma unroll
        for (int j = 0; j < 8; ++j) { st[j] = 0.f; st2[j] = 0.f; }
    }

    for (int node = gw; node < n; node += nw) {
        int beg = __builtin_amdgcn_readfirstlane(row_ptr[node]);
        int end = __builtin_amdgcn_readfirstlane(row_ptr[node + 1]);

        float a[8];
        #pragma unroll
        for (int j = 0; j < 8; ++j) a[j] = 0.f;

        // prefetch first batch's payload (8+8 edge slots)
        int i0 = beg + sub, i1 = beg + 8 + sub;
        bool v0 = i0 < end, v1 = i1 < end;
        int p0 = v0 ? payload[i0] : 0;
        int p1 = v1 ? payload[i1] : 0;

        for (int e = beg; e < end; e += 16) {
            int  q0 = p0,  q1 = p1;
            bool w0 = v0,  w1 = v1;
            // prefetch next batch's payload while row loads are in flight
            int ni0 = e + 16 + sub, ni1 = e + 24 + sub;
            v0 = ni0 < end; v1 = ni1 < end;
            p0 = v0 ? payload[ni0] : 0;
            p1 = v1 ? payload[ni1] : 0;

            int r0 = w0 ? (q0 & 0x7fffffff) : node;   // clamp to hot row
            int r1 = w1 ? (q1 & 0x7fffffff) : node;
            uint4 u0 = *(const uint4*)(valb + (size_t)r0 * 64 + c0);
            uint4 u1 = *(const uint4*)(valb + (size_t)r1 * 64 + c0);
            float s0 = w0 ? ((SAGE && q0 < 0) ? -1.f : 1.f) : 0.f;
            float s1 = w1 ? ((SAGE && q1 < 0) ? -1.f : 1.f) : 0.f;
            accum8(a, u0, s0);
            accum8(a, u1, s1);
        }

        // fold the 8 edge slots (lane-xor 8/16/32); all lanes end with totals
        #pragma unroll
        for (int j = 0; j < 8; ++j) {
            a[j] += __shfl_xor(a[j], 8, 64);
            a[j] += __shfl_xor(a[j], 16, 64);
            a[j] += __shfl_xor(a[j], 32, 64);
        }

        if (sub == 0) {   // lanes 0..7 hold the full row between them
            uint4 us = *(const uint4*)(valb + (size_t)node * 64 + c0);
            a[0] += __uint_as_float(us.x << 16);
            a[1] += __uint_as_float(us.x & 0xffff0000u);
            a[2] += __uint_as_float(us.y << 16);
            a[3] += __uint_as_float(us.y & 0xffff0000u);
            a[4] += __uint_as_float(us.z << 16);
            a[5] += __uint_as_float(us.z & 0xffff0000u);
            a[6] += __uint_as_float(us.w << 16);
            a[7] += __uint_as_float(us.w & 0xffff0000u);
            if (SAGE) {
                float rd = rdeg[node];
                float4 xp0 = *(const float4*)(xprev + (size_t)node * 64 + c0);
                float4 xp1 = *(const float4*)(xprev + (size_t)node * 64 + c0 + 4);
                float xp[8] = {xp0.x, xp0.y, xp0.z, xp0.w,
                               xp1.x, xp1.y, xp1.z, xp1.w};
                #pragma unroll
                for (int j = 0; j < 8; ++j) {
                    float h = fmaf(a[j], rd, xp[j]);
                    st[j]  += h;
                    st2[j] += h * h;
                    a[j] = h;
                }
            }
            *(float4*)(out + (size_t)node * 64 + c0) =
                make_float4(a[0], a[1], a[2], a[3]);
            *(float4*)(out + (size_t)node * 64 + c0 + 4) =
                make_float4(a[4], a[5], a[6], a[7]);
        }
    }

    if (SAGE) {
        __shared__ float sh[2][4][64];
        if (sub == 0) {
            #pragma unroll
            for (int j = 0; j < 8; ++j) {
                sh[0][wid][c0 + j] = st[j];
                sh[1][wid][c0 + j] = st2[j];
            }
        }
        __syncthreads();
        if (tid < 64) {
            float a_ = sh[0][0][tid] + sh[0][1][tid] + sh[0][2][tid] + sh[0][3][tid];
            float b_ = sh[1][0][tid] + sh[1][1][tid] + sh[1][2][tid] + sh[1][3][tid];
            atomicAdd(colsum + tid, a_);
            atomicAdd(colsumsq + tid, b_);
        }
    }
}

// ---------------- readout stage 1: H = relu(LN(x @ W1 + b1)) -----------------
__global__ __launch_bounds__(256) void readout1(
    const float* __restrict__ xf, const float* __restrict__ W1,
    const float* __restrict__ b1, const float* __restrict__ g1,
    const float* __restrict__ bt1, float* __restrict__ H, int n)
{
    __shared__ __align__(16) float At[64][68];
    __shared__ __align__(16) float Ws[64][132];
    const int tid = threadIdx.x;
    const int tx = tid & 15, ty = tid >> 4;
    const int rowBase = blockIdx.x * 64;

    #pragma unroll
    for (int i = 0; i < 4; ++i) {
        int v = tid + i * 256;
        int r = v >> 4, k4 = (v & 15) * 4;
        float4 a = make_float4(0.f, 0.f, 0.f, 0.f);
        int grow = rowBase + r;
        if (grow < n) a = *(const float4*)(xf + (size_t)grow * 64 + k4);
        At[k4 + 0][r] = a.x; At[k4 + 1][r] = a.y;
        At[k4 + 2][r] = a.z; At[k4 + 3][r] = a.w;
    }
    #pragma unroll
    for (int i = 0; i < 8; ++i) {
        int v = tid + i * 256;
        int k = v >> 5, c4 = (v & 31) * 4;
        *(float4*)&Ws[k][c4] = *(const float4*)(W1 + k * 128 + c4);
    }
    __syncthreads();

    const int r0 = ty * 4, c0 = tx * 8;
    float acc[4][8];
    #pragma unroll
    for (int j = 0; j < 8; ++j) {
        float bv = b1[c0 + j];
        #pragma unroll
        for (int i = 0; i < 4; ++i) acc[i][j] = bv;
    }
    #pragma unroll 8
    for (int k = 0; k < 64; ++k) {
        float4 av = *(const float4*)&At[k][r0];
        float4 w0 = *(const float4*)&Ws[k][c0];
        float4 w1v = *(const float4*)&Ws[k][c0 + 4];
        float a4[4] = {av.x, av.y, av.z, av.w};
        float w8[8] = {w0.x, w0.y, w0.z, w0.w, w1v.x, w1v.y, w1v.z, w1v.w};
        #pragma unroll
        for (int i = 0; i < 4; ++i)
            #pragma unroll
            for (int j = 0; j < 8; ++j)
                acc[i][j] = fmaf(a4[i], w8[j], acc[i][j]);
    }

    float gj[8], bj[8];
    #pragma unroll
    for (int j = 0; j < 8; ++j) { gj[j] = g1[c0 + j]; bj[j] = bt1[c0 + j]; }
    #pragma unroll
    for (int i = 0; i < 4; ++i) {
        int grow = rowBase + r0 + i;
        float s = 0.f, s2 = 0.f;
        #pragma unroll
        for (int j = 0; j < 8; ++j) { s += acc[i][j]; s2 += acc[i][j] * acc[i][j]; }
        #pragma unroll
        for (int off = 8; off; off >>= 1) {
            s  += __shfl_xor(s, off, 16);
            s2 += __shfl_xor(s2, off, 16);
        }
        float mean = s * (1.f / 128.f);
        float var  = s2 * (1.f / 128.f) - mean * mean;
        float rstd = rsqrtf(var + 1e-5f);
        float o[8];
        #pragma unroll
        for (int j = 0; j < 8; ++j)
            o[j] = fmaxf(fmaf((acc[i][j] - mean) * rstd, gj[j], bj[j]), 0.f);
        if (grow < n) {
            *(float4*)(H + (size_t)grow * 128 + c0)     = make_float4(o[0], o[1], o[2], o[3]);
            *(float4*)(H + (size_t)grow * 128 + c0 + 4) = make_float4(o[4], o[5], o[6], o[7]);
        }
    }
}

// ------- readout stage 2: prob = sigmoid(relu(LN(H @ W2 + b2)) @ W3 + b3) ----
__global__ __launch_bounds__(256) void readout2(
    const float* __restrict__ H, const float* __restrict__ W2,
    const float* __restrict__ b2, const float* __restrict__ g2,
    const float* __restrict__ bt2, const float* __restrict__ W3,
    const float* __restrict__ b3, float* __restrict__ prob, int n)
{
    __shared__ __align__(16) float Ht[64][68];
    __shared__ __align__(16) float Ws[64][132];
    const int tid = threadIdx.x;
    const int tx = tid & 15, ty = tid >> 4;
    const int rowBase = blockIdx.x * 64;
    const int r0 = ty * 4, c0 = tx * 8;

    float acc[4][8];
    #pragma unroll
    for (int j = 0; j < 8; ++j) {
        float bv = b2[c0 + j];
        #pragma unroll
        for (int i = 0; i < 4; ++i) acc[i][j] = bv;
    }

    for (int kc = 0; kc < 2; ++kc) {
        if (kc) __syncthreads();
        #pragma unroll
        for (int i = 0; i < 4; ++i) {
            int v = tid + i * 256;
            int r = v >> 4, k4 = (v & 15) * 4;
            float4 a = make_float4(0.f, 0.f, 0.f, 0.f);
            int grow = rowBase + r;
            if (grow < n) a = *(const float4*)(H + (size_t)grow * 128 + kc * 64 + k4);
            Ht[k4 + 0][r] = a.x; Ht[k4 + 1][r] = a.y;
            Ht[k4 + 2][r] = a.z; Ht[k4 + 3][r] = a.w;
        }
        #pragma unroll
        for (int i = 0; i < 8; ++i) {
            int v = tid + i * 256;
            int k = v >> 5, c4 = (v & 31) * 4;
            *(float4*)&Ws[k][c4] = *(const float4*)(W2 + (kc * 64 + k) * 128 + c4);
        }
        __syncthreads();
        #pragma unroll 8
        for (int k = 0; k < 64; ++k) {
            float4 av = *(const float4*)&Ht[k][r0];
            float4 w0 = *(const float4*)&Ws[k][c0];
            float4 w1v = *(const float4*)&Ws[k][c0 + 4];
            float a4[4] = {av.x, av.y, av.z, av.w};
            float w8[8] = {w0.x, w0.y, w0.z, w0.w, w1v.x, w1v.y, w1v.z, w1v.w};
            #pragma unroll
            for (int i = 0; i < 4; ++i)
                #pragma unroll
                for (int j = 0; j < 8; ++j)
                    acc[i][j] = fmaf(a4[i], w8[j], acc[i][j]);
        }
    }

    float gj[8], bj[8], w3[8];
    #pragma unroll
    for (int j = 0; j < 8; ++j) {
        gj[j] = g2[c0 + j]; bj[j] = bt2[c0 + j]; w3[j] = W3[c0 + j];
    }
    const float bias3 = b3[0];
    #pragma unroll
    for (int i = 0; i < 4; ++i) {
        int grow = rowBase + r0 + i;
        float s = 0.f, s2 = 0.f;
        #pragma unroll
        for (int j = 0; j < 8; ++j) { s += acc[i][j]; s2 += acc[i][j] * acc[i][j]; }
        #pragma unroll
        for (int off = 8; off; off >>= 1) {
            s  += __shfl_xor(s, off, 16);
            s2 += __shfl_xor(s2, off, 16);
        }
        float mean = s * (1.f / 128.f);
        float var  = s2 * (1.f / 128.f) - mean * mean;
        float rstd = rsqrtf(var + 1e-5f);
        float d = 0.f;
        #pragma unroll
        for (int j = 0; j < 8; ++j) {
            float v = fmaxf(fmaf((acc[i][j] - mean) * rstd, gj[j], bj[j]), 0.f);
            d = fmaf(v, w3[j], d);
        }
        #pragma unroll
        for (int off = 8; off; off >>= 1) d += __shfl_xor(d, off, 16);
        if (tx == 0 && grow < n)
            prob[grow] = 1.f / (1.f + expf(-(d + bias3)));
    }
}

// ---------------------------------------------------------------------------
extern "C" void kernel_launch(void* const* d_in, const int* in_sizes, int n_in,
                              void* d_out, int out_size, void* d_ws, size_t ws_size,
                              hipStream_t stream)
{
    const float* init_emb = (const float*)d_in[0];
    const int*   eidx     = (const int*)d_in[1];
    const float* rate_b   = (const float*)d_in[2];
    const float* sage_W   = (const float*)d_in[3];
    const float* sage_b   = (const float*)d_in[4];
    const float* norm_w   = (const float*)d_in[5];
    const float* norm_b   = (const float*)d_in[6];
    const float* rs_w     = (const float*)d_in[7];
    const float* rs_b     = (const float*)d_in[8];
    const float* rb_w     = (const float*)d_in[9];
    const float* rb_b     = (const float*)d_in[10];
    const float* gin_W1   = (const float*)d_in[11];
    const float* gin_b1   = (const float*)d_in[12];
    const float* gin_W2   = (const float*)d_in[13];
    const float* gin_b2   = (const float*)d_in[14];
    const float* fuse_W   = (const float*)d_in[15];
    const float* fuse_b   = (const float*)d_in[16];
    const float* ro_W1    = (const float*)d_in[17];
    const float* ro_b1    = (const float*)d_in[18];
    const float* ln1_g    = (const float*)d_in[19];
    const float* ln1_b    = (const float*)d_in[20];
    const float* ro_W2    = (const float*)d_in[21];
    const float* ro_b2    = (const float*)d_in[22];
    const float* ln2_g    = (const float*)d_in[23];
    const float* ln2_b    = (const float*)d_in[24];
    const float* ro_W3    = (const float*)d_in[25];
    const float* ro_b3    = (const float*)d_in[26];

    const int N = in_sizes[0] / 64;
    const int E = in_sizes[1] / 3;
    const size_t nf = (size_t)N * 64;

    float* bufA  = (float*)d_ws;             // H region (with bufB) at readout
    float* bufB  = bufA + nf;
    float* bufC  = bufB + nf;
    unsigned short* bfbuf = (unsigned short*)(bufC + nf);  // nf bf16
    float* rdeg  = (float*)(bfbuf + nf);     // N floats
    float* stats = rdeg + N;                 // 3 x (colsum64|colsumsq64|pad)
    int*   row_ptr  = (int*)(stats + 3 * 256);   // N+1
    int*   deg_i    = row_ptr + (N + 1);         // N
    int*   blocksum = deg_i + N;                 // 256
    int*   blockoff = blocksum + 256;            // 256
    int*   bucket_cursor = blockoff + 256;       // <=256
    int*   payload  = bucket_cursor + 256;       // E
    uint2* inter    = (uint2*)bufC;              // aliases bufC (dead until p=1)

    float* xfinal = (float*)d_out;           // N x 64
    float* prob   = xfinal + nf;             // N
    float* H      = bufA;                    // N x 128 (bufA+bufB)

    const int gemm_blocks = (N + 63) / 64;
    const int gather_blocks = 2048;
    const int chunk  = (N + 255) / 256;
    const float inv_n = 1.0f / (float)N;

    const int Bn   = (N + NBSIZE - 1) / NBSIZE;
    const int meanb = (E + Bn - 1) / Bn;
    const int cap  = meanb + meanb / 8 + 64;
    const int ablocks = (E + 4095) / 4096;

    // ---- CSR build (bucket-sorted, deterministic) ----
    hipMemsetAsync(stats, 0, 3 * 256 * sizeof(float), stream);
    init_buckets<<<1, 256, 0, stream>>>(bucket_cursor, Bn, cap);
    bucketA<<<ablocks, 256, 0, stream>>>(eidx, bucket_cursor, inter, E);
    bucketB1<<<Bn, 256, 0, stream>>>(inter, bucket_cursor, deg_i, cap, N);
    scan1<<<256, 256, 0, stream>>>(deg_i, blocksum, N, chunk);
    scan2<<<1, 256, 0, stream>>>(blocksum, blockoff, row_ptr + N);
    scan3<<<256, 256, 0, stream>>>(deg_i, blockoff, row_ptr, rdeg, N, chunk);
    bucketB2<<<Bn, 256, 0, stream>>>(inter, bucket_cursor, row_ptr, payload, cap, N);

    for (int p = 0; p < 3; ++p) {
        const float* Xp = (p == 0) ? init_emb : (p == 1 ? (const float*)bufB : (const float*)bufC);
        float* B2p = (p == 1) ? bufC : bufB;
        float* cs = stats + p * 256;

        // 1. bfbuf = bf16(Xp @ W + b): explicit GEMM only for p=0; pairs 1,2
        //    get bfbuf from the previous gin_fuse's fused GEMM4.
        if (p == 0)
            gemm64<<<gemm_blocks, 256, 0, stream>>>(
                Xp, sage_W, sage_b, bfbuf, N);
        // 2. B2p = (xt + sum sign*xt[src]) * rdeg + Xp ; column stats
        gather64<true><<<gather_blocks, 256, 0, stream>>>(
            row_ptr, payload, bfbuf, Xp, rdeg, B2p, cs, cs + 64, N);
        // 3. bfbuf = bf16(gelu(norm(h))); xfinal (+)= x @ fuse_W[2p]
        if (p == 0)
            act_fuse<true><<<gemm_blocks, 256, 0, stream>>>(
                B2p, cs, cs + 64,
                norm_w + p * 64, norm_b + p * 64, rs_w + p * 64, rs_b + p * 64,
                rb_w + p * 64, rb_b + p * 64, rate_b, inv_n,
                fuse_W, fuse_b, bfbuf, xfinal, N);
        else
            act_fuse<false><<<gemm_blocks, 256, 0, stream>>>(
                B2p, cs, cs + 64,
                norm_w + p * 64, norm_b + p * 64, rs_w + p * 64, rs_b + p * 64,
                rb_w + p * 64, rb_b + p * 64, rate_b, inv_n,
                fuse_W + (2 * p) * 4096, nullptr, bfbuf, xfinal, N);
        // 4. B2p = x + sum x[src]   (z, from bf16 x copy)
        gather64<false><<<gather_blocks, 256, 0, stream>>>(
            row_ptr, payload, bfbuf, nullptr, nullptr, B2p, nullptr, nullptr, N);
        // 5. gin: B2p = gelu(z@W1+b1)@W2+b2 ; xfinal += B2p@fuse ;
        //    p<2: bfbuf = bf16(B2p @ sage_W[p+1] + sage_b[p+1])
        if (p < 2)
            gin_fuse<true><<<gemm_blocks, 256, 0, stream>>>(
                B2p, gin_W1 + p * 4096, gin_b1 + p * 64,
                gin_W2 + p * 4096, gin_b2 + p * 64,
                fuse_W + (2 * p + 1) * 4096,
                sage_W + (p + 1) * 4096, sage_b + (p + 1) * 64,
                B2p, xfinal, bfbuf, N);
        else
            gin_fuse<false><<<gemm_blocks, 256, 0, stream>>>(
                B2p, gin_W1 + p * 4096, gin_b1 + p * 64,
                gin_W2 + p * 4096, gin_b2 + p * 64,
                fuse_W + (2 * p + 1) * 4096,
                nullptr, nullptr, B2p, xfinal, nullptr, N);
    }

    // ---- readout ----
    readout1<<<gemm_blocks, 256, 0, stream>>>(
        xfinal, ro_W1, ro_b1, ln1_g, ln1_b, H, N);
    readout2<<<gemm_blocks, 256, 0, stream>>>(
        H, ro_W2, ro_b2, ln2_g, ln2_b, ro_W3, ro_b3, prob, N);
}

// Round 3
// 822.655 us; speedup vs baseline: 1.1171x; 1.1171x over previous
//
#include <hip/hip_runtime.h>
#include <hip/hip_bf16.h>
#include <math.h>

// ---------------------------------------------------------------------------
// FuncGNN R15: gather = 8 nodes/wave, one node per 8-lane group. Lane 8g+j
// owns cols [8j,8j+8) of group-g's node -> accumulation is lane-private, NO
// cross-lane reduction per node (R14's 24 shfl/node gone). Wave-uniform edge
// loop (trip = max over groups, padded slots clamp to self-row w/ scale 0),
// 4 edges/group/iter unroll -> 32 independent row loads in flight per wave
// (vs <=8 in R13/R14). Payload quad prefetched one iteration ahead.
// Everything outside gather64 identical to R13 (867.8 us baseline).
// ---------------------------------------------------------------------------

#define NBSHIFT 9           // 512 nodes per bucket
#define NBSIZE  512

__device__ __forceinline__ float gelu_f(float x) {
    return 0.5f * x * (1.0f + erff(x * 0.70710678118654752440f));
}
__device__ __forceinline__ unsigned short f2bf(float x) {
    __hip_bfloat16 h = __float2bfloat16(x);      // RNE
    return *reinterpret_cast<unsigned short*>(&h);
}
__device__ __forceinline__ unsigned pack2bf(float a, float b) {
    return (unsigned)f2bf(a) | ((unsigned)f2bf(b) << 16);
}
__device__ __forceinline__ float bf2f(unsigned short u) {
    return __uint_as_float((unsigned)u << 16);
}

// ------------- gemm64: Cb[n,64](bf16) = A @ Wa + ba  (p=0 only) --------------
__global__ __launch_bounds__(256) void gemm64(
    const float* __restrict__ A,
    const float* __restrict__ Wa, const float* __restrict__ ba,
    unsigned short* __restrict__ Cb, int n)
{
    __shared__ __align__(16) float At[64][68];
    __shared__ __align__(16) float Ws[64][68];
    const int tid = threadIdx.x;
    const int tx = tid & 15, ty = tid >> 4;
    const int rowBase = blockIdx.x * 64;

    #pragma unroll
    for (int i = 0; i < 4; ++i) {
        int v  = tid + i * 256;
        int r  = v >> 4;
        int k4 = (v & 15) * 4;
        float4 a = make_float4(0.f, 0.f, 0.f, 0.f);
        int grow = rowBase + r;
        if (grow < n) a = *(const float4*)(A + (size_t)grow * 64 + k4);
        At[k4 + 0][r] = a.x; At[k4 + 1][r] = a.y;
        At[k4 + 2][r] = a.z; At[k4 + 3][r] = a.w;
        *(float4*)&Ws[r][k4] = *(const float4*)(Wa + r * 64 + k4);
    }
    __syncthreads();

    const int r0 = ty * 4, c0 = tx * 4;
    float acc[4][4];
    #pragma unroll
    for (int j = 0; j < 4; ++j) {
        float bv = ba[c0 + j];
        #pragma unroll
        for (int i = 0; i < 4; ++i) acc[i][j] = bv;
    }
    #pragma unroll 16
    for (int k = 0; k < 64; ++k) {
        float4 av = *(const float4*)&At[k][r0];
        float4 wv = *(const float4*)&Ws[k][c0];
        float a4[4] = {av.x, av.y, av.z, av.w};
        float w4[4] = {wv.x, wv.y, wv.z, wv.w};
        #pragma unroll
        for (int i = 0; i < 4; ++i)
            #pragma unroll
            for (int j = 0; j < 4; ++j)
                acc[i][j] = fmaf(a4[i], w4[j], acc[i][j]);
    }
    #pragma unroll
    for (int i = 0; i < 4; ++i) {
        int grow = rowBase + r0 + i;
        if (grow < n) {
            uint2 u;
            u.x = pack2bf(acc[i][0], acc[i][1]);
            u.y = pack2bf(acc[i][2], acc[i][3]);
            *(uint2*)(Cb + (size_t)grow * 64 + c0) = u;
        }
    }
}

// -- act_fuse: graph-norm scale/offset in-block; x=gelu(h*a+b) (bf16 only);
//    xfinal (+)= x @ Wf (+bf if FIRST) ---------------------------------------
template<bool FIRST>
__global__ __launch_bounds__(256) void act_fuse(
    const float* __restrict__ h,
    const float* __restrict__ colsum, const float* __restrict__ colsumsq,
    const float* __restrict__ nw, const float* __restrict__ nb,
    const float* __restrict__ rsw, const float* __restrict__ rsb,
    const float* __restrict__ rbw, const float* __restrict__ rbb,
    const float* __restrict__ rate_p, float inv_n,
    const float* __restrict__ Wf, const float* __restrict__ bf,
    unsigned short* __restrict__ xb, float* __restrict__ xfinal, int n)
{
    __shared__ __align__(16) float At[64][68];
    __shared__ __align__(16) float Ws[64][68];
    __shared__ float ab_s[128];
    const int tid = threadIdx.x;
    const int tx = tid & 15, ty = tid >> 4;
    const int rowBase = blockIdx.x * 64;

    if (tid < 64) {
        float mean = colsum[tid] * inv_n;
        float var  = colsumsq[tid] * inv_n - mean * mean;
        float rstd = rsqrtf(var + 1e-5f);
        float rate = rate_p[0];
        float gamma = nw[tid] + (rsw[tid] * rate + rsb[tid]);
        float beta  = nb[tid] + (rbw[tid] * rate + rbb[tid]);
        float a = rstd * gamma;
        ab_s[tid] = a;
        ab_s[64 + tid] = beta - mean * a;
    }
    __syncthreads();

    #pragma unroll
    for (int i = 0; i < 4; ++i) {
        int v  = tid + i * 256;
        int r  = v >> 4;
        int k4 = (v & 15) * 4;
        int grow = rowBase + r;
        float4 a = make_float4(0.f, 0.f, 0.f, 0.f);
        if (grow < n) {
            float4 hv = *(const float4*)(h + (size_t)grow * 64 + k4);
            a.x = gelu_f(fmaf(hv.x, ab_s[k4 + 0], ab_s[64 + k4 + 0]));
            a.y = gelu_f(fmaf(hv.y, ab_s[k4 + 1], ab_s[64 + k4 + 1]));
            a.z = gelu_f(fmaf(hv.z, ab_s[k4 + 2], ab_s[64 + k4 + 2]));
            a.w = gelu_f(fmaf(hv.w, ab_s[k4 + 3], ab_s[64 + k4 + 3]));
            uint2 u;
            u.x = pack2bf(a.x, a.y);
            u.y = pack2bf(a.z, a.w);
            *(uint2*)(xb + (size_t)grow * 64 + k4) = u;
        }
        At[k4 + 0][r] = a.x; At[k4 + 1][r] = a.y;
        At[k4 + 2][r] = a.z; At[k4 + 3][r] = a.w;
        *(float4*)&Ws[r][k4] = *(const float4*)(Wf + r * 64 + k4);
    }
    __syncthreads();

    const int r0 = ty * 4, c0 = tx * 4;
    float acc[4][4];
    if (FIRST) {
        #pragma unroll
        for (int j = 0; j < 4; ++j) {
            float bv = bf[c0 + j];
            #pragma unroll
            for (int i = 0; i < 4; ++i) acc[i][j] = bv;
        }
    } else {
        #pragma unroll
        for (int i = 0; i < 4; ++i)
            #pragma unroll
            for (int j = 0; j < 4; ++j) acc[i][j] = 0.f;
    }
    #pragma unroll 16
    for (int k = 0; k < 64; ++k) {
        float4 av = *(const float4*)&At[k][r0];
        float4 wv = *(const float4*)&Ws[k][c0];
        float a4[4] = {av.x, av.y, av.z, av.w};
        float w4[4] = {wv.x, wv.y, wv.z, wv.w};
        #pragma unroll
        for (int i = 0; i < 4; ++i)
            #pragma unroll
            for (int j = 0; j < 4; ++j)
                acc[i][j] = fmaf(a4[i], w4[j], acc[i][j]);
    }
    #pragma unroll
    for (int i = 0; i < 4; ++i) {
        int grow = rowBase + r0 + i;
        if (grow < n) {
            float4 r = make_float4(acc[i][0], acc[i][1], acc[i][2], acc[i][3]);
            float* cp = xfinal + (size_t)grow * 64 + c0;
            if (!FIRST) {
                float4 c = *(const float4*)cp;
                r.x += c.x; r.y += c.y; r.z += c.z; r.w += c.w;
            }
            *(float4*)cp = r;
        }
    }
}

// -- gin_fuse: t=gelu(z@W1+b1); o=t@W2+b2 -> xout; xfinal += o@Wf;
//    if NEXT: bfout = bf16(o @ Wn + bn)   (next pair's SAGE xt) --------------
template<bool NEXT>
__global__ __launch_bounds__(256) void gin_fuse(
    const float* __restrict__ z,
    const float* __restrict__ W1, const float* __restrict__ b1,
    const float* __restrict__ W2, const float* __restrict__ b2,
    const float* __restrict__ Wf,
    const float* __restrict__ Wn, const float* __restrict__ bn,
    float* __restrict__ xout, float* __restrict__ xfinal,
    unsigned short* __restrict__ bfout, int n)
{
    __shared__ __align__(16) float At[64][68];
    __shared__ __align__(16) float Ws[64][68];
    const int tid = threadIdx.x;
    const int tx = tid & 15, ty = tid >> 4;
    const int rowBase = blockIdx.x * 64;
    const int r0 = ty * 4, c0 = tx * 4;

    #pragma unroll
    for (int i = 0; i < 4; ++i) {
        int v  = tid + i * 256;
        int r  = v >> 4;
        int k4 = (v & 15) * 4;
        float4 a = make_float4(0.f, 0.f, 0.f, 0.f);
        int grow = rowBase + r;
        if (grow < n) a = *(const float4*)(z + (size_t)grow * 64 + k4);
        At[k4 + 0][r] = a.x; At[k4 + 1][r] = a.y;
        At[k4 + 2][r] = a.z; At[k4 + 3][r] = a.w;
        *(float4*)&Ws[r][k4] = *(const float4*)(W1 + r * 64 + k4);
    }
    __syncthreads();

    float acc[4][4];
    #pragma unroll
    for (int j = 0; j < 4; ++j) {
        float bv = b1[c0 + j];
        #pragma unroll
        for (int i = 0; i < 4; ++i) acc[i][j] = bv;
    }
    #pragma unroll 16
    for (int k = 0; k < 64; ++k) {
        float4 av = *(const float4*)&At[k][r0];
        float4 wv = *(const float4*)&Ws[k][c0];
        float a4[4] = {av.x, av.y, av.z, av.w};
        float w4[4] = {wv.x, wv.y, wv.z, wv.w};
        #pragma unroll
        for (int i = 0; i < 4; ++i)
            #pragma unroll
            for (int j = 0; j < 4; ++j)
                acc[i][j] = fmaf(a4[i], w4[j], acc[i][j]);
    }

    // ---- GEMM2: gelu(acc) @ W2 + b2
    __syncthreads();
    #pragma unroll
    for (int i = 0; i < 4; ++i)
        #pragma unroll
        for (int j = 0; j < 4; ++j)
            At[c0 + j][r0 + i] = gelu_f(acc[i][j]);
    #pragma unroll
    for (int i = 0; i < 4; ++i) {
        int v = tid + i * 256;
        int k = v >> 4, c4 = (v & 15) * 4;
        *(float4*)&Ws[k][c4] = *(const float4*)(W2 + k * 64 + c4);
    }
    __syncthreads();
    float acc2[4][4];
    #pragma unroll
    for (int j = 0; j < 4; ++j) {
        float bv = b2[c0 + j];
        #pragma unroll
        for (int i = 0; i < 4; ++i) acc2[i][j] = bv;
    }
    #pragma unroll 16
    for (int k = 0; k < 64; ++k) {
        float4 av = *(const float4*)&At[k][r0];
        float4 wv = *(const float4*)&Ws[k][c0];
        float a4[4] = {av.x, av.y, av.z, av.w};
        float w4[4] = {wv.x, wv.y, wv.z, wv.w};
        #pragma unroll
        for (int i = 0; i < 4; ++i)
            #pragma unroll
            for (int j = 0; j < 4; ++j)
                acc2[i][j] = fmaf(a4[i], w4[j], acc2[i][j]);
    }
    #pragma unroll
    for (int i = 0; i < 4; ++i) {
        int grow = rowBase + r0 + i;
        if (grow < n)
            *(float4*)(xout + (size_t)grow * 64 + c0) =
                make_float4(acc2[i][0], acc2[i][1], acc2[i][2], acc2[i][3]);
    }

    // ---- GEMM3: xfinal += acc2 @ Wf   (At <- acc2^T, reused by GEMM4)
    __syncthreads();
    #pragma unroll
    for (int i = 0; i < 4; ++i)
        #pragma unroll
        for (int j = 0; j < 4; ++j)
            At[c0 + j][r0 + i] = acc2[i][j];
    #pragma unroll
    for (int i = 0; i < 4; ++i) {
        int v = tid + i * 256;
        int k = v >> 4, c4 = (v & 15) * 4;
        *(float4*)&Ws[k][c4] = *(const float4*)(Wf + k * 64 + c4);
    }
    __syncthreads();
    float acc3[4][4];
    #pragma unroll
    for (int i = 0; i < 4; ++i)
        #pragma unroll
        for (int j = 0; j < 4; ++j) acc3[i][j] = 0.f;
    #pragma unroll 16
    for (int k = 0; k < 64; ++k) {
        float4 av = *(const float4*)&At[k][r0];
        float4 wv = *(const float4*)&Ws[k][c0];
        float a4[4] = {av.x, av.y, av.z, av.w};
        float w4[4] = {wv.x, wv.y, wv.z, wv.w};
        #pragma unroll
        for (int i = 0; i < 4; ++i)
            #pragma unroll
            for (int j = 0; j < 4; ++j)
                acc3[i][j] = fmaf(a4[i], w4[j], acc3[i][j]);
    }
    #pragma unroll
    for (int i = 0; i < 4; ++i) {
        int grow = rowBase + r0 + i;
        if (grow < n) {
            float* cp = xfinal + (size_t)grow * 64 + c0;
            float4 c = *(const float4*)cp;
            c.x += acc3[i][0]; c.y += acc3[i][1];
            c.z += acc3[i][2]; c.w += acc3[i][3];
            *(float4*)cp = c;
        }
    }

    if (NEXT) {
        // ---- GEMM4: bfout = bf16(acc2 @ Wn + bn); At still holds acc2^T
        __syncthreads();
        #pragma unroll
        for (int i = 0; i < 4; ++i) {
            int v = tid + i * 256;
            int k = v >> 4, c4 = (v & 15) * 4;
            *(float4*)&Ws[k][c4] = *(const float4*)(Wn + k * 64 + c4);
        }
        __syncthreads();
        float acc4[4][4];
        #pragma unroll
        for (int j = 0; j < 4; ++j) {
            float bv = bn[c0 + j];
            #pragma unroll
            for (int i = 0; i < 4; ++i) acc4[i][j] = bv;
        }
        #pragma unroll 16
        for (int k = 0; k < 64; ++k) {
            float4 av = *(const float4*)&At[k][r0];
            float4 wv = *(const float4*)&Ws[k][c0];
            float a4[4] = {av.x, av.y, av.z, av.w};
            float w4[4] = {wv.x, wv.y, wv.z, wv.w};
            #pragma unroll
            for (int i = 0; i < 4; ++i)
                #pragma unroll
                for (int j = 0; j < 4; ++j)
                    acc4[i][j] = fmaf(a4[i], w4[j], acc4[i][j]);
        }
        #pragma unroll
        for (int i = 0; i < 4; ++i) {
            int grow = rowBase + r0 + i;
            if (grow < n) {
                uint2 u;
                u.x = pack2bf(acc4[i][0], acc4[i][1]);
                u.y = pack2bf(acc4[i][2], acc4[i][3]);
                *(uint2*)(bfout + (size_t)grow * 64 + c0) = u;
            }
        }
    }
}

// ---------------- bucket-sorted CSR build ------------------------------------
__global__ void init_buckets(int* __restrict__ bucket_cursor, int Bn, int cap) {
    int t = threadIdx.x;
    if (t < Bn) bucket_cursor[t] = t * cap;
}

__global__ __launch_bounds__(256) void bucketA(
    const int* __restrict__ eidx, int* __restrict__ bucket_cursor,
    uint2* __restrict__ inter, int E)
{
    __shared__ int cnt[256], lo[256], cur[256], garr[256];
    __shared__ int tot_s;
    __shared__ uint2 stage[4096];
    const int tid = threadIdx.x;
    cnt[tid] = 0;
    __syncthreads();

    const int base = blockIdx.x * 4096;
    int pay[16], dfull[16];
    #pragma unroll
    for (int i = 0; i < 16; ++i) {
        int e = base + i * 256 + tid;
        dfull[i] = -1;
        if (e < E) {
            int s  = __builtin_nontemporal_load(eidx + e * 3 + 0);
            int d  = __builtin_nontemporal_load(eidx + e * 3 + 1);
            int sg = __builtin_nontemporal_load(eidx + e * 3 + 2);
            if (sg < 0) s |= 0x80000000;
            pay[i] = s;
            dfull[i] = d;
            atomicAdd(&cnt[d >> NBSHIFT], 1);
        }
    }
    __syncthreads();

    lo[tid] = cnt[tid];
    __syncthreads();
    for (int off = 1; off < 256; off <<= 1) {
        int t = (tid >= off) ? lo[tid - off] : 0;
        __syncthreads();
        lo[tid] += t;
        __syncthreads();
    }
    if (tid == 255) tot_s = lo[255];
    int excl = lo[tid] - cnt[tid];
    __syncthreads();
    lo[tid] = excl;
    cur[tid] = 0;
    if (cnt[tid] > 0) garr[tid] = atomicAdd(bucket_cursor + tid, cnt[tid]);
    __syncthreads();

    #pragma unroll
    for (int i = 0; i < 16; ++i) {
        if (dfull[i] >= 0) {
            int k = dfull[i] >> NBSHIFT;
            int r = atomicAdd(&cur[k], 1);
            stage[lo[k] + r] = make_uint2((unsigned)pay[i], (unsigned)dfull[i]);
        }
    }
    __syncthreads();

    const int tot = tot_s;
    for (int i = tid; i < tot; i += 256) {
        uint2 en = stage[i];
        int k = (int)(en.y >> NBSHIFT);
        inter[garr[k] + (i - lo[k])] = en;
    }
}

__global__ __launch_bounds__(256) void bucketB1(
    const uint2* __restrict__ inter, const int* __restrict__ bucket_cursor,
    int* __restrict__ deg_i, int cap, int n)
{
    __shared__ int cnt[NBSIZE];
    const int b = blockIdx.x, tid = threadIdx.x;
    cnt[tid] = 0; cnt[tid + 256] = 0;
    __syncthreads();
    const int base = b * cap;
    const int len = bucket_cursor[b] - base;
    for (int i = tid; i < len; i += 256)
        atomicAdd(&cnt[inter[base + i].y & (NBSIZE - 1)], 1);
    __syncthreads();
    const int nb0 = b << NBSHIFT;
    if (nb0 + tid < n)       deg_i[nb0 + tid]       = cnt[tid];
    if (nb0 + 256 + tid < n) deg_i[nb0 + 256 + tid] = cnt[256 + tid];
}

__global__ __launch_bounds__(256) void bucketB2(
    const uint2* __restrict__ inter, const int* __restrict__ bucket_cursor,
    const int* __restrict__ row_ptr, int* __restrict__ payload, int cap, int n)
{
    __shared__ int cur[NBSIZE];
    const int b = blockIdx.x, tid = threadIdx.x;
    const int nb0 = b << NBSHIFT;
    cur[tid]       = (nb0 + tid < n)       ? row_ptr[nb0 + tid]       : 0;
    cur[tid + 256] = (nb0 + 256 + tid < n) ? row_ptr[nb0 + 256 + tid] : 0;
    __syncthreads();
    const int base = b * cap;
    const int len = bucket_cursor[b] - base;
    for (int i = tid; i < len; i += 256) {
        uint2 en = inter[base + i];
        int pos = atomicAdd(&cur[en.y & (NBSIZE - 1)], 1);
        payload[pos] = (int)en.x;
    }
}

// ---------------- scans ------------------------------------------------------
__global__ __launch_bounds__(256) void scan1(
    const int* __restrict__ deg_i, int* __restrict__ blocksum, int n, int chunk)
{
    int b = blockIdx.x;
    int lo = b * chunk, hi = min(lo + chunk, n);
    int s = 0;
    for (int i = lo + (int)threadIdx.x; i < hi; i += 256) s += deg_i[i];
    #pragma unroll
    for (int off = 32; off; off >>= 1) s += __shfl_xor(s, off, 64);
    __shared__ int ws[4];
    if ((threadIdx.x & 63) == 0) ws[threadIdx.x >> 6] = s;
    __syncthreads();
    if (threadIdx.x == 0) blocksum[b] = ws[0] + ws[1] + ws[2] + ws[3];
}

__global__ __launch_bounds__(256) void scan2(
    const int* __restrict__ blocksum, int* __restrict__ blockoff,
    int* __restrict__ row_ptr_n)
{
    int tid = threadIdx.x, lane = tid & 63, wid = tid >> 6;
    int orig = blocksum[tid];
    int v = orig;
    #pragma unroll
    for (int off = 1; off < 64; off <<= 1) {
        int t = __shfl_up(v, off, 64);
        if (lane >= off) v += t;
    }
    __shared__ int wt[4];
    if (lane == 63) wt[wid] = v;
    __syncthreads();
    int woff = 0;
    for (int w = 0; w < wid; ++w) woff += wt[w];
    blockoff[tid] = woff + v - orig;
    if (tid == 255) *row_ptr_n = woff + v;
}

__global__ __launch_bounds__(256) void scan3(
    const int* __restrict__ deg_i, const int* __restrict__ blockoff,
    int* __restrict__ row_ptr, float* __restrict__ rdeg, int n, int chunk)
{
    int b = blockIdx.x;
    int lo = b * chunk, hi = min(lo + chunk, n);
    int carry = blockoff[b];
    int tid = threadIdx.x, lane = tid & 63, wid = tid >> 6;
    __shared__ int wt[4];
    for (int base = lo; base < hi; base += 256) {
        int i = base + tid;
        int orig = (i < hi) ? deg_i[i] : 0;
        int v = orig;
        #pragma unroll
        for (int off = 1; off < 64; off <<= 1) {
            int t = __shfl_up(v, off, 64);
            if (lane >= off) v += t;
        }
        if (lane == 63) wt[wid] = v;
        __syncthreads();
        int woff = 0;
        for (int w = 0; w < wid; ++w) woff += wt[w];
        int tot = wt[0] + wt[1] + wt[2] + wt[3];
        int excl = carry + woff + (v - orig);
        if (i < hi) {
            row_ptr[i] = excl;
            rdeg[i]    = 1.0f / ((float)orig + 1.0f);
        }
        carry += tot;
        __syncthreads();
    }
}

// ------- gather R15: 8 nodes/wave (8-lane group per node), lane-private
//         accumulation, uniform trip count, 4-deep edge unroll --------------
__device__ __forceinline__ void accum8(float* a, uint4 u, float s) {
    a[0] = fmaf(__uint_as_float(u.x << 16),          s, a[0]);
    a[1] = fmaf(__uint_as_float(u.x & 0xffff0000u),  s, a[1]);
    a[2] = fmaf(__uint_as_float(u.y << 16),          s, a[2]);
    a[3] = fmaf(__uint_as_float(u.y & 0xffff0000u),  s, a[3]);
    a[4] = fmaf(__uint_as_float(u.z << 16),          s, a[4]);
    a[5] = fmaf(__uint_as_float(u.z & 0xffff0000u),  s, a[5]);
    a[6] = fmaf(__uint_as_float(u.w << 16),          s, a[6]);
    a[7] = fmaf(__uint_as_float(u.w & 0xffff0000u),  s, a[7]);
}

template<bool SAGE>
__global__ __launch_bounds__(256) void gather64(
    const int* __restrict__ row_ptr, const int* __restrict__ payload,
    const unsigned short* __restrict__ valb, const float* __restrict__ xprev,
    const float* __restrict__ rdeg, float* __restrict__ out,
    float* __restrict__ colsum, float* __restrict__ colsumsq, int n)
{
    const int tid  = threadIdx.x;
    const int lane = tid & 63;
    const int j8   = lane & 7;           // col sub-slot
    const int c0   = j8 * 8;             // cols [c0, c0+8)
    const int wid  = tid >> 6;
    const int gg0  = (blockIdx.x * 256 + tid) >> 3;   // global group id
    const int ng   = (gridDim.x * 256) >> 3;          // total groups

    float st[8], st2[8];
    if (SAGE) {
        #pragma unroll
        for (int k = 0; k < 8; ++k) { st[k] = 0.f; st2[k] = 0.f; }
    }

    for (int node = gg0; __any(node < n); node += ng) {
        const bool active  = node < n;
        const int  selfrow = active ? node : 0;
        const int  beg     = active ? row_ptr[node]     : 0;
        const int  end     = active ? row_ptr[node + 1] : 0;

        // wave-uniform trip count = max over the 8 groups
        int t = (end - beg + 3) >> 2;
        t = max(t, __shfl_xor(t, 8, 64));
        t = max(t, __shfl_xor(t, 16, 64));
        t = max(t, __shfl_xor(t, 32, 64));

        float a[8];
        #pragma unroll
        for (int k = 0; k < 8; ++k) a[k] = 0.f;

        // prefetch payload quad for it=0
        int p0 = (beg + 0 < end) ? payload[beg + 0] : 0;
        int p1 = (beg + 1 < end) ? payload[beg + 1] : 0;
        int p2 = (beg + 2 < end) ? payload[beg + 2] : 0;
        int p3 = (beg + 3 < end) ? payload[beg + 3] : 0;

        for (int it = 0; it < t; ++it) {
            const int i0 = beg + (it << 2);
            const bool w0 = i0 + 0 < end, w1 = i0 + 1 < end;
            const bool w2 = i0 + 2 < end, w3 = i0 + 3 < end;
            const int q0 = p0, q1 = p1, q2 = p2, q3 = p3;

            // issue 4 independent row loads (8 rows per instr across groups)
            const int r0 = w0 ? (q0 & 0x7fffffff) : selfrow;
            const int r1 = w1 ? (q1 & 0x7fffffff) : selfrow;
            const int r2 = w2 ? (q2 & 0x7fffffff) : selfrow;
            const int r3 = w3 ? (q3 & 0x7fffffff) : selfrow;
            uint4 u0 = *(const uint4*)(valb + (size_t)r0 * 64 + c0);
            uint4 u1 = *(const uint4*)(valb + (size_t)r1 * 64 + c0);
            uint4 u2 = *(const uint4*)(valb + (size_t)r2 * 64 + c0);
            uint4 u3 = *(const uint4*)(valb + (size_t)r3 * 64 + c0);

            // prefetch next iteration's payload quad while rows are in flight
            const int nb = i0 + 4;
            p0 = (nb + 0 < end) ? payload[nb + 0] : 0;
            p1 = (nb + 1 < end) ? payload[nb + 1] : 0;
            p2 = (nb + 2 < end) ? payload[nb + 2] : 0;
            p3 = (nb + 3 < end) ? payload[nb + 3] : 0;

            const float s0 = w0 ? ((SAGE && q0 < 0) ? -1.f : 1.f) : 0.f;
            const float s1 = w1 ? ((SAGE && q1 < 0) ? -1.f : 1.f) : 0.f;
            const float s2 = w2 ? ((SAGE && q2 < 0) ? -1.f : 1.f) : 0.f;
            const float s3 = w3 ? ((SAGE && q3 < 0) ? -1.f : 1.f) : 0.f;
            accum8(a, u0, s0);
            accum8(a, u1, s1);
            accum8(a, u2, s2);
            accum8(a, u3, s3);
        }

        // self row (xt for SAGE, x for GIN)
        uint4 us = *(const uint4*)(valb + (size_t)selfrow * 64 + c0);
        accum8(a, us, 1.f);

        if (SAGE) {
            const float rd = active ? rdeg[node] : 0.f;
            float4 xp0 = *(const float4*)(xprev + (size_t)selfrow * 64 + c0);
            float4 xp1 = *(const float4*)(xprev + (size_t)selfrow * 64 + c0 + 4);
            float xp[8] = {xp0.x, xp0.y, xp0.z, xp0.w,
                           xp1.x, xp1.y, xp1.z, xp1.w};
            float h[8];
            #pragma unroll
            for (int k = 0; k < 8; ++k) h[k] = fmaf(a[k], rd, xp[k]);
            if (active) {
                #pragma unroll
                for (int k = 0; k < 8; ++k) {
                    st[k]  += h[k];
                    st2[k] += h[k] * h[k];
                }
                *(float4*)(out + (size_t)node * 64 + c0) =
                    make_float4(h[0], h[1], h[2], h[3]);
                *(float4*)(out + (size_t)node * 64 + c0 + 4) =
                    make_float4(h[4], h[5], h[6], h[7]);
            }
        } else {
            if (active) {
                *(float4*)(out + (size_t)node * 64 + c0) =
                    make_float4(a[0], a[1], a[2], a[3]);
                *(float4*)(out + (size_t)node * 64 + c0 + 4) =
                    make_float4(a[4], a[5], a[6], a[7]);
            }
        }
    }

    if (SAGE) {
        // fold the 8 groups (lane-xor 8/16/32); each j8-class ends identical
        #pragma unroll
        for (int k = 0; k < 8; ++k) {
            st[k]  += __shfl_xor(st[k], 8, 64);
            st[k]  += __shfl_xor(st[k], 16, 64);
            st[k]  += __shfl_xor(st[k], 32, 64);
            st2[k] += __shfl_xor(st2[k], 8, 64);
            st2[k] += __shfl_xor(st2[k], 16, 64);
            st2[k] += __shfl_xor(st2[k], 32, 64);
        }
        __shared__ float sh[2][4][64];
        if (lane < 8) {
            #pragma unroll
            for (int k = 0; k < 8; ++k) {
                sh[0][wid][c0 + k] = st[k];
                sh[1][wid][c0 + k] = st2[k];
            }
        }
        __syncthreads();
        if (tid < 64) {
            float a_ = sh[0][0][tid] + sh[0][1][tid] + sh[0][2][tid] + sh[0][3][tid];
            float b_ = sh[1][0][tid] + sh[1][1][tid] + sh[1][2][tid] + sh[1][3][tid];
            atomicAdd(colsum + tid, a_);
            atomicAdd(colsumsq + tid, b_);
        }
    }
}

// ---------------- readout stage 1: H = relu(LN(x @ W1 + b1)) -----------------
__global__ __launch_bounds__(256) void readout1(
    const float* __restrict__ xf, const float* __restrict__ W1,
    const float* __restrict__ b1, const float* __restrict__ g1,
    const float* __restrict__ bt1, float* __restrict__ H, int n)
{
    __shared__ __align__(16) float At[64][68];
    __shared__ __align__(16) float Ws[64][132];
    const int tid = threadIdx.x;
    const int tx = tid & 15, ty = tid >> 4;
    const int rowBase = blockIdx.x * 64;

    #pragma unroll
    for (int i = 0; i < 4; ++i) {
        int v = tid + i * 256;
        int r = v >> 4, k4 = (v & 15) * 4;
        float4 a = make_float4(0.f, 0.f, 0.f, 0.f);
        int grow = rowBase + r;
        if (grow < n) a = *(const float4*)(xf + (size_t)grow * 64 + k4);
        At[k4 + 0][r] = a.x; At[k4 + 1][r] = a.y;
        At[k4 + 2][r] = a.z; At[k4 + 3][r] = a.w;
    }
    #pragma unroll
    for (int i = 0; i < 8; ++i) {
        int v = tid + i * 256;
        int k = v >> 5, c4 = (v & 31) * 4;
        *(float4*)&Ws[k][c4] = *(const float4*)(W1 + k * 128 + c4);
    }
    __syncthreads();

    const int r0 = ty * 4, c0 = tx * 8;
    float acc[4][8];
    #pragma unroll
    for (int j = 0; j < 8; ++j) {
        float bv = b1[c0 + j];
        #pragma unroll
        for (int i = 0; i < 4; ++i) acc[i][j] = bv;
    }
    #pragma unroll 8
    for (int k = 0; k < 64; ++k) {
        float4 av = *(const float4*)&At[k][r0];
        float4 w0 = *(const float4*)&Ws[k][c0];
        float4 w1v = *(const float4*)&Ws[k][c0 + 4];
        float a4[4] = {av.x, av.y, av.z, av.w};
        float w8[8] = {w0.x, w0.y, w0.z, w0.w, w1v.x, w1v.y, w1v.z, w1v.w};
        #pragma unroll
        for (int i = 0; i < 4; ++i)
            #pragma unroll
            for (int j = 0; j < 8; ++j)
                acc[i][j] = fmaf(a4[i], w8[j], acc[i][j]);
    }

    float gj[8], bj[8];
    #pragma unroll
    for (int j = 0; j < 8; ++j) { gj[j] = g1[c0 + j]; bj[j] = bt1[c0 + j]; }
    #pragma unroll
    for (int i = 0; i < 4; ++i) {
        int grow = rowBase + r0 + i;
        float s = 0.f, s2 = 0.f;
        #pragma unroll
        for (int j = 0; j < 8; ++j) { s += acc[i][j]; s2 += acc[i][j] * acc[i][j]; }
        #pragma unroll
        for (int off = 8; off; off >>= 1) {
            s  += __shfl_xor(s, off, 16);
            s2 += __shfl_xor(s2, off, 16);
        }
        float mean = s * (1.f / 128.f);
        float var  = s2 * (1.f / 128.f) - mean * mean;
        float rstd = rsqrtf(var + 1e-5f);
        float o[8];
        #pragma unroll
        for (int j = 0; j < 8; ++j)
            o[j] = fmaxf(fmaf((acc[i][j] - mean) * rstd, gj[j], bj[j]), 0.f);
        if (grow < n) {
            *(float4*)(H + (size_t)grow * 128 + c0)     = make_float4(o[0], o[1], o[2], o[3]);
            *(float4*)(H + (size_t)grow * 128 + c0 + 4) = make_float4(o[4], o[5], o[6], o[7]);
        }
    }
}

// ------- readout stage 2: prob = sigmoid(relu(LN(H @ W2 + b2)) @ W3 + b3) ----
__global__ __launch_bounds__(256) void readout2(
    const float* __restrict__ H, const float* __restrict__ W2,
    const float* __restrict__ b2, const float* __restrict__ g2,
    const float* __restrict__ bt2, const float* __restrict__ W3,
    const float* __restrict__ b3, float* __restrict__ prob, int n)
{
    __shared__ __align__(16) float Ht[64][68];
    __shared__ __align__(16) float Ws[64][132];
    const int tid = threadIdx.x;
    const int tx = tid & 15, ty = tid >> 4;
    const int rowBase = blockIdx.x * 64;
    const int r0 = ty * 4, c0 = tx * 8;

    float acc[4][8];
    #pragma unroll
    for (int j = 0; j < 8; ++j) {
        float bv = b2[c0 + j];
        #pragma unroll
        for (int i = 0; i < 4; ++i) acc[i][j] = bv;
    }

    for (int kc = 0; kc < 2; ++kc) {
        if (kc) __syncthreads();
        #pragma unroll
        for (int i = 0; i < 4; ++i) {
            int v = tid + i * 256;
            int r = v >> 4, k4 = (v & 15) * 4;
            float4 a = make_float4(0.f, 0.f, 0.f, 0.f);
            int grow = rowBase + r;
            if (grow < n) a = *(const float4*)(H + (size_t)grow * 128 + kc * 64 + k4);
            Ht[k4 + 0][r] = a.x; Ht[k4 + 1][r] = a.y;
            Ht[k4 + 2][r] = a.z; Ht[k4 + 3][r] = a.w;
        }
        #pragma unroll
        for (int i = 0; i < 8; ++i) {
            int v = tid + i * 256;
            int k = v >> 5, c4 = (v & 31) * 4;
            *(float4*)&Ws[k][c4] = *(const float4*)(W2 + (kc * 64 + k) * 128 + c4);
        }
        __syncthreads();
        #pragma unroll 8
        for (int k = 0; k < 64; ++k) {
            float4 av = *(const float4*)&Ht[k][r0];
            float4 w0 = *(const float4*)&Ws[k][c0];
            float4 w1v = *(const float4*)&Ws[k][c0 + 4];
            float a4[4] = {av.x, av.y, av.z, av.w};
            float w8[8] = {w0.x, w0.y, w0.z, w0.w, w1v.x, w1v.y, w1v.z, w1v.w};
            #pragma unroll
            for (int i = 0; i < 4; ++i)
                #pragma unroll
                for (int j = 0; j < 8; ++j)
                    acc[i][j] = fmaf(a4[i], w8[j], acc[i][j]);
        }
    }

    float gj[8], bj[8], w3[8];
    #pragma unroll
    for (int j = 0; j < 8; ++j) {
        gj[j] = g2[c0 + j]; bj[j] = bt2[c0 + j]; w3[j] = W3[c0 + j];
    }
    const float bias3 = b3[0];
    #pragma unroll
    for (int i = 0; i < 4; ++i) {
        int grow = rowBase + r0 + i;
        float s = 0.f, s2 = 0.f;
        #pragma unroll
        for (int j = 0; j < 8; ++j) { s += acc[i][j]; s2 += acc[i][j] * acc[i][j]; }
        #pragma unroll
        for (int off = 8; off; off >>= 1) {
            s  += __shfl_xor(s, off, 16);
            s2 += __shfl_xor(s2, off, 16);
        }
        float mean = s * (1.f / 128.f);
        float var  = s2 * (1.f / 128.f) - mean * mean;
        float rstd = rsqrtf(var + 1e-5f);
        float d = 0.f;
        #pragma unroll
        for (int j = 0; j < 8; ++j) {
            float v = fmaxf(fmaf((acc[i][j] - mean) * rstd, gj[j], bj[j]), 0.f);
            d = fmaf(v, w3[j], d);
        }
        #pragma unroll
        for (int off = 8; off; off >>= 1) d += __shfl_xor(d, off, 16);
        if (tx == 0 && grow < n)
            prob[grow] = 1.f / (1.f + expf(-(d + bias3)));
    }
}

// ---------------------------------------------------------------------------
extern "C" void kernel_launch(void* const* d_in, const int* in_sizes, int n_in,
                              void* d_out, int out_size, void* d_ws, size_t ws_size,
                              hipStream_t stream)
{
    const float* init_emb = (const float*)d_in[0];
    const int*   eidx     = (const int*)d_in[1];
    const float* rate_b   = (const float*)d_in[2];
    const float* sage_W   = (const float*)d_in[3];
    const float* sage_b   = (const float*)d_in[4];
    const float* norm_w   = (const float*)d_in[5];
    const float* norm_b   = (const float*)d_in[6];
    const float* rs_w     = (const float*)d_in[7];
    const float* rs_b     = (const float*)d_in[8];
    const float* rb_w     = (const float*)d_in[9];
    const float* rb_b     = (const float*)d_in[10];
    const float* gin_W1   = (const float*)d_in[11];
    const float* gin_b1   = (const float*)d_in[12];
    const float* gin_W2   = (const float*)d_in[13];
    const float* gin_b2   = (const float*)d_in[14];
    const float* fuse_W   = (const float*)d_in[15];
    const float* fuse_b   = (const float*)d_in[16];
    const float* ro_W1    = (const float*)d_in[17];
    const float* ro_b1    = (const float*)d_in[18];
    const float* ln1_g    = (const float*)d_in[19];
    const float* ln1_b    = (const float*)d_in[20];
    const float* ro_W2    = (const float*)d_in[21];
    const float* ro_b2    = (const float*)d_in[22];
    const float* ln2_g    = (const float*)d_in[23];
    const float* ln2_b    = (const float*)d_in[24];
    const float* ro_W3    = (const float*)d_in[25];
    const float* ro_b3    = (const float*)d_in[26];

    const int N = in_sizes[0] / 64;
    const int E = in_sizes[1] / 3;
    const size_t nf = (size_t)N * 64;

    float* bufA  = (float*)d_ws;             // H region (with bufB) at readout
    float* bufB  = bufA + nf;
    float* bufC  = bufB + nf;
    unsigned short* bfbuf = (unsigned short*)(bufC + nf);  // nf bf16
    float* rdeg  = (float*)(bfbuf + nf);     // N floats
    float* stats = rdeg + N;                 // 3 x (colsum64|colsumsq64|pad)
    int*   row_ptr  = (int*)(stats + 3 * 256);   // N+1
    int*   deg_i    = row_ptr + (N + 1);         // N
    int*   blocksum = deg_i + N;                 // 256
    int*   blockoff = blocksum + 256;            // 256
    int*   bucket_cursor = blockoff + 256;       // <=256
    int*   payload  = bucket_cursor + 256;       // E
    uint2* inter    = (uint2*)bufC;              // aliases bufC (dead until p=1)

    float* xfinal = (float*)d_out;           // N x 64
    float* prob   = xfinal + nf;             // N
    float* H      = bufA;                    // N x 128 (bufA+bufB)

    const int gemm_blocks = (N + 63) / 64;
    const int gather_blocks = 2048;
    const int chunk  = (N + 255) / 256;
    const float inv_n = 1.0f / (float)N;

    const int Bn   = (N + NBSIZE - 1) / NBSIZE;
    const int meanb = (E + Bn - 1) / Bn;
    const int cap  = meanb + meanb / 8 + 64;
    const int ablocks = (E + 4095) / 4096;

    // ---- CSR build (bucket-sorted, deterministic) ----
    hipMemsetAsync(stats, 0, 3 * 256 * sizeof(float), stream);
    init_buckets<<<1, 256, 0, stream>>>(bucket_cursor, Bn, cap);
    bucketA<<<ablocks, 256, 0, stream>>>(eidx, bucket_cursor, inter, E);
    bucketB1<<<Bn, 256, 0, stream>>>(inter, bucket_cursor, deg_i, cap, N);
    scan1<<<256, 256, 0, stream>>>(deg_i, blocksum, N, chunk);
    scan2<<<1, 256, 0, stream>>>(blocksum, blockoff, row_ptr + N);
    scan3<<<256, 256, 0, stream>>>(deg_i, blockoff, row_ptr, rdeg, N, chunk);
    bucketB2<<<Bn, 256, 0, stream>>>(inter, bucket_cursor, row_ptr, payload, cap, N);

    for (int p = 0; p < 3; ++p) {
        const float* Xp = (p == 0) ? init_emb : (p == 1 ? (const float*)bufB : (const float*)bufC);
        float* B2p = (p == 1) ? bufC : bufB;
        float* cs = stats + p * 256;

        // 1. bfbuf = bf16(Xp @ W + b): explicit GEMM only for p=0; pairs 1,2
        //    get bfbuf from the previous gin_fuse's fused GEMM4.
        if (p == 0)
            gemm64<<<gemm_blocks, 256, 0, stream>>>(
                Xp, sage_W, sage_b, bfbuf, N);
        // 2. B2p = (xt + sum sign*xt[src]) * rdeg + Xp ; column stats
        gather64<true><<<gather_blocks, 256, 0, stream>>>(
            row_ptr, payload, bfbuf, Xp, rdeg, B2p, cs, cs + 64, N);
        // 3. bfbuf = bf16(gelu(norm(h))); xfinal (+)= x @ fuse_W[2p]
        if (p == 0)
            act_fuse<true><<<gemm_blocks, 256, 0, stream>>>(
                B2p, cs, cs + 64,
                norm_w + p * 64, norm_b + p * 64, rs_w + p * 64, rs_b + p * 64,
                rb_w + p * 64, rb_b + p * 64, rate_b, inv_n,
                fuse_W, fuse_b, bfbuf, xfinal, N);
        else
            act_fuse<false><<<gemm_blocks, 256, 0, stream>>>(
                B2p, cs, cs + 64,
                norm_w + p * 64, norm_b + p * 64, rs_w + p * 64, rs_b + p * 64,
                rb_w + p * 64, rb_b + p * 64, rate_b, inv_n,
                fuse_W + (2 * p) * 4096, nullptr, bfbuf, xfinal, N);
        // 4. B2p = x + sum x[src]   (z, from bf16 x copy)
        gather64<false><<<gather_blocks, 256, 0, stream>>>(
            row_ptr, payload, bfbuf, nullptr, nullptr, B2p, nullptr, nullptr, N);
        // 5. gin: B2p = gelu(z@W1+b1)@W2+b2 ; xfinal += B2p@fuse ;
        //    p<2: bfbuf = bf16(B2p @ sage_W[p+1] + sage_b[p+1])
        if (p < 2)
            gin_fuse<true><<<gemm_blocks, 256, 0, stream>>>(
                B2p, gin_W1 + p * 4096, gin_b1 + p * 64,
                gin_W2 + p * 4096, gin_b2 + p * 64,
                fuse_W + (2 * p + 1) * 4096,
                sage_W + (p + 1) * 4096, sage_b + (p + 1) * 64,
                B2p, xfinal, bfbuf, N);
        else
            gin_fuse<false><<<gemm_blocks, 256, 0, stream>>>(
                B2p, gin_W1 + p * 4096, gin_b1 + p * 64,
                gin_W2 + p * 4096, gin_b2 + p * 64,
                fuse_W + (2 * p + 1) * 4096,
                nullptr, nullptr, B2p, xfinal, nullptr, N);
    }

    // ---- readout ----
    readout1<<<gemm_blocks, 256, 0, stream>>>(
        xfinal, ro_W1, ro_b1, ln1_g, ln1_b, H, N);
    readout2<<<gemm_blocks, 256, 0, stream>>>(
        H, ro_W2, ro_b2, ln2_g, ln2_b, ro_W3, ro_b3, prob, N);
}